// Round 2
// baseline (116.135 us; speedup 1.0000x reference)
//
#include <hip/hip_runtime.h>

#define D_ 128
#define N_ 8192
#define K_ 256

typedef __attribute__((ext_vector_type(4))) float f4;    // 4 fp32
typedef __attribute__((ext_vector_type(8))) int i8v;     // 8 x i32 (MFMA operand)
typedef __attribute__((ext_vector_type(4))) int i4v;     // 4 x i32 (16 B)

// ---------------------------------------------------------------------------
// fp6 e2m3 helpers. Code: bit5 sign, bits4:3 exponent E (bias 1), bits2:0 M.
// Values: E=0 -> M/8 (subnormal, step .125, max .875); E>=1 -> (8+M)/8 * 2^(E-1).
// Max 7.5. Encoded value set = {0..15}/8  U  {16..30 step2}/8  U  {32..60 step4}/8.
__device__ __forceinline__ int enc6(float v) {
  unsigned s = (__float_as_uint(v) >> 31) << 5;
  float a = fminf(fabsf(v), 7.5f);
  int code;
  if (a < 2.f) {
    code = (int)rintf(a * 8.f);              // 0..16 ; 16 == (2<<3)|0 == 2.0 OK
  } else if (a < 4.f) {
    code = 16 + ((int)rintf(a * 4.f) - 8);   // 16..24 ; 24 == (3<<3)|0 == 4.0 OK
  } else {
    code = 24 + ((int)rintf(a * 2.f) - 8);   // 24..31 (7.5 -> 31)
  }
  return code | (int)s;
}

__device__ __forceinline__ float dec6(int c) {
  int M = c & 7, E = (c >> 3) & 3;
  int mant = (E == 0) ? M : (8 + M);
  float sc = (E <= 1) ? 0.125f : (E == 2 ? 0.25f : 0.5f);
  float v = (float)mant * sc;
  return (c & 32) ? -v : v;
}

// ---------------------------------------------------------------------------
// prep_k: fused prep_x + prep_a(+amu). Flat grid of 512 blocks.
//   blocks 0..255   : X (fp32 [D][N]) -> Xf6 (fp6, [n][4 q-chunks of 32B], 24 B
//                     data + 8 B pad per chunk) + exact fp32 copy of X into out.
//   blocks 256..511 : N_A -> Af6s (fp6 codes of 8*A, frag-ordered, 12288 B/plane:
//                     region0 [dtl][L][16B] then region1 [dtl][L][8B]) + fused
//                     negated amu computed from the DECODED fp6 values (so the
//                     MFMA C-operand is exactly consistent with quantized A).
// A is pre-scaled by 8 before encoding (8A ~ N(0,0.71) fits e2m3's 7.5 max);
// sq comes out scaled by 64, folded into gamma (exact pow2) in softmax_k.
__global__ __launch_bounds__(256) void prep_k(
    const float* __restrict__ X, float* __restrict__ out,
    unsigned char* __restrict__ Xf6, const float* __restrict__ NA,
    unsigned char* __restrict__ Af6s, const float* __restrict__ Nmu,
    float* __restrict__ Amut) {
  __shared__ __align__(16) char smem[21568];
  const int t = threadIdx.x;
  const int id = blockIdx.x;

  if (id < 256) {
    // ---------------- prep_x role ----------------
    float (*tile)[65] = (float (*)[65])smem;   // 64 x 65 floats = 16.6 KB
    const int n0 = (id & 127) * 64;
    const int e0 = (id >> 7) * 64;
    const int col = t & 63;
    const int r4 = t >> 6;
    for (int rr = 0; rr < 64; rr += 4) {
      int e = rr + r4;
      float v = X[(size_t)(e0 + e) * N_ + n0 + col];
      tile[e][col] = v;
      out[(size_t)(e0 + e) * N_ + n0 + col] = v;   // exact fp32 copy of X
    }
    __syncthreads();
    // fp6 pack: 256 tasks = 64 n x 2 q-chunks x 2 halves (16 elements = 96 bits)
    const int nl = t >> 2;
    const int ql = (t >> 1) & 1;
    const int h = t & 1;
    unsigned long long lo = 0; unsigned int hi = 0;
#pragma unroll
    for (int j = 0; j < 16; ++j) {
      unsigned long long c = (unsigned long long)enc6(tile[ql * 32 + h * 16 + j][nl]);
      const int pos = 6 * j;
      if (pos <= 58) {
        lo |= c << pos;
        if (pos == 60) hi |= (unsigned int)(c >> 4);   // unreachable here, kept simple
      } else if (pos < 64) {
        lo |= c << pos;
        hi |= (unsigned int)(c >> (64 - pos));
      } else {
        hi |= (unsigned int)(c << (pos - 64));
      }
    }
    unsigned char* dst = Xf6 + (size_t)(n0 + nl) * 128 + (e0 / 32 + ql) * 32 + h * 12;
    *(unsigned int*)(dst + 0) = (unsigned int)lo;
    *(unsigned int*)(dst + 4) = (unsigned int)(lo >> 32);
    *(unsigned int*)(dst + 8) = hi;
  } else {
    // ---------------- prep_a (+amu) role ----------------
    const int aid = id - 256;
    const int dtl = aid & 7;           // d-tile of 16
    const int c0 = (aid >> 3) * 8;     // 8 c per block (32 groups)
    unsigned char* AT = (unsigned char*)smem;        // fp6 CODES [cl][d*136+e], 8*2184=17472 B
    float* mu_s = (float*)(smem + 17472);            // [cl][e], 8*128*4 = 4096 B
    {
      const int cl = t & 7;
      const int er = t >> 3;
#pragma unroll
      for (int pass = 0; pass < 4; ++pass) {
        int e = pass * 32 + er;
        mu_s[cl * 128 + e] = Nmu[(size_t)e * K_ + c0 + cl];
      }
    }
    // load + encode A*8 -> fp6 codes; float4 across 4 consecutive c
    const int c4 = t & 1;
    const int pe = t >> 1;
#pragma unroll 4
    for (int iter = 0; iter < 16; ++iter) {
      int p = iter * 128 + pe;
      int d = p >> 7, e = p & 127;
      float4 v = *(const float4*)&NA[((size_t)(dtl * 16 + d) * D_ + e) * K_ + c0 + c4 * 4];
      AT[(c4 * 4 + 0) * 2184 + d * 136 + e] = (unsigned char)enc6(v.x * 8.f);
      AT[(c4 * 4 + 1) * 2184 + d * 136 + e] = (unsigned char)enc6(v.y * 8.f);
      AT[(c4 * 4 + 2) * 2184 + d * 136 + e] = (unsigned char)enc6(v.z * 8.f);
      AT[(c4 * 4 + 3) * 2184 + d * 136 + e] = (unsigned char)enc6(v.w * 8.f);
    }
    __syncthreads();
    // fused amu from DECODED (x8-scaled) values; negated for the MFMA C-operand
    if (t < 128) {
      const int d_loc = t >> 3;
      const int cl = t & 7;
      const unsigned char* row = &AT[cl * 2184 + d_loc * 136];
      const float* mr = &mu_s[cl * 128];
      float s = 0.f;
#pragma unroll
      for (int j = 0; j < 16; ++j) {             // 16 x int2 (8 codes each)
        int2 v = *(const int2*)(row + j * 8);
        const int e0i = j * 8;
        s += dec6(v.x & 63) * mr[e0i + 0];
        s += dec6((v.x >> 8) & 63) * mr[e0i + 1];
        s += dec6((v.x >> 16) & 63) * mr[e0i + 2];
        s += dec6((v.x >> 24) & 63) * mr[e0i + 3];
        s += dec6(v.y & 63) * mr[e0i + 4];
        s += dec6((v.y >> 8) & 63) * mr[e0i + 5];
        s += dec6((v.y >> 16) & 63) * mr[e0i + 6];
        s += dec6((v.y >> 24) & 63) * mr[e0i + 7];
      }
      Amut[(size_t)(c0 + cl) * D_ + dtl * 16 + d_loc] = -s;
    }
    // write phase: 512 tasks (cl 0..7 x L 0..63): pack lane L's 32 codes
    // (row m=L&15, elements k=(L>>4)*32 + 0..31) into 24 B = 192 bits.
#pragma unroll
    for (int r = 0; r < 2; ++r) {
      const int task = r * 256 + t;
      const int cl = task >> 6;
      const int L = task & 63;
      const unsigned char* cp = AT + cl * 2184 + (L & 15) * 136 + (L >> 4) * 32;
      unsigned long long w0 = 0, w1 = 0, w2 = 0;
#pragma unroll
      for (int g = 0; g < 4; ++g) {             // 4 x int2 = 8 dwords of 4 codes
        int2 dv = *(const int2*)(cp + g * 8);
#pragma unroll
        for (int half = 0; half < 2; ++half) {
          unsigned int d = (half == 0) ? (unsigned int)dv.x : (unsigned int)dv.y;
          unsigned long long g24 =
              (unsigned long long)((d & 63u) | ((d >> 8) & 63u) << 6 |
                                   ((d >> 16) & 63u) << 12 | ((d >> 24) & 63u) << 18);
          const int pos = (g * 2 + half) * 24;
          if (pos < 64) {
            w0 |= g24 << pos;
            if (pos > 40) w1 |= g24 >> (64 - pos);
          } else if (pos < 128) {
            w1 |= g24 << (pos - 64);
            if (pos - 64 > 40) w2 |= g24 >> (128 - pos);
          } else {
            w2 |= g24 << (pos - 128);
          }
        }
      }
      unsigned char* plane = Af6s + (size_t)(c0 + cl) * 12288;
      ulonglong2 val; val.x = w0; val.y = w1;
      *(ulonglong2*)(plane + dtl * 1024 + L * 16) = val;                 // region0
      *(unsigned long long*)(plane + 8192 + dtl * 512 + L * 8) = w2;     // region1
    }
  }
}

// ---------------------------------------------------------------------------
// main (MX-fp6 e2m3, K=128 per instruction, cbsz=blgp=2): rate 7287 TF vs
// fp8's 4661 -> compute floor 14.7 -> 9.4 us. Plane = 12288 B (region0
// [dtl][L][16B], region1 [dtl][L][8B]); lane frag = 24 B = 6 VGPRs, dense
// 6-bit LSB-first packing. Structure (double-buffered full-plane staging,
// barrier per plane, XCD-swizzled flat grid) unchanged from the verified
// fp8 version.
__global__ __launch_bounds__(256, 4) void main_k(
    const unsigned char* __restrict__ Af6s, const unsigned char* __restrict__ Xf6,
    const float* __restrict__ Amut, float* __restrict__ sqws) {
  __shared__ unsigned char A0s[12288];
  __shared__ unsigned char A1s[12288];
  __shared__ float amus[2][D_];
  const int t = threadIdx.x;
  const int w = t >> 6;
  const int L = t & 63;
  const int m = L & 15;
  const int q = L >> 4;

  const int id = blockIdx.x;
  const int xcd = id & 7;
  const int s = id >> 3;
  const int yb = xcd * 4 + (s & 3);   // c-group 0..31 (4 per XCD)
  const int xb = s >> 2;              // n-tile 0..31
  const int n0 = xb * 256;
  const int c0 = yb * 8;

  // persistent X B-frags: lane holds n = n0+w*64+jt*16+m, k = q*32 + [0..31]
  i8v xf[4];
#pragma unroll
  for (int jt = 0; jt < 4; ++jt) {
    const unsigned char* xr = Xf6 + (size_t)(n0 + w * 64 + jt * 16 + m) * 128 + q * 32;
    i4v x0 = *(const i4v*)(xr);
    int2 x1 = *(const int2*)(xr + 16);
    i8v f;
    f[0] = x0[0]; f[1] = x0[1]; f[2] = x0[2]; f[3] = x0[3];
    f[4] = x1.x;  f[5] = x1.y;  f[6] = 0;     f[7] = 0;
    xf[jt] = f;
  }

  const unsigned char* pl = Af6s + (size_t)c0 * 12288;

#define STAGE(SRC, DST)                                                          \
  {                                                                              \
    _Pragma("unroll")                                                            \
    for (int it_ = 0; it_ < 3; ++it_)                                            \
      __builtin_amdgcn_global_load_lds(                                          \
          (const unsigned int*)((SRC) + (it_ * 256 + t) * 16),                   \
          (unsigned int*)((DST) + (it_ * 256 + w * 64) * 16), 16, 0, 0);         \
  }

  STAGE(pl, A0s);
  if (t < 32)
    __builtin_amdgcn_global_load_lds((const unsigned int*)(Amut + (size_t)c0 * D_ + t * 4),
                                     (unsigned int*)&amus[0][0], 16, 0, 0);

  auto compute = [&](const unsigned char* buf, const float* amurow, int c) {
    float ss0 = 0.f, ss1 = 0.f, ss2 = 0.f, ss3 = 0.f;
#pragma unroll
    for (int dtl = 0; dtl < 8; ++dtl) {
      i4v p0 = *(const i4v*)(buf + dtl * 1024 + L * 16);            // bits 0..127
      int2 p1 = *(const int2*)(buf + 8192 + dtl * 512 + L * 8);     // bits 128..191
      i8v a;
      a[0] = p0[0]; a[1] = p0[1]; a[2] = p0[2]; a[3] = p0[3];
      a[4] = p1.x;  a[5] = p1.y;  a[6] = 0;     a[7] = 0;
      f4 camu = *(const f4*)&amurow[dtl * 16 + q * 4];   // = -(8A)_q . mu slice
#pragma unroll
      for (int jt = 0; jt < 4; ++jt) {
        f4 acc = __builtin_amdgcn_mfma_scale_f32_16x16x128_f8f6f4(
            a, xf[jt], camu, 2, 2, 0, 0x7f7f7f7f, 0, 0x7f7f7f7f);
        float sj = acc[0] * acc[0] + acc[1] * acc[1] + acc[2] * acc[2] + acc[3] * acc[3];
        if (jt == 0) ss0 += sj; else if (jt == 1) ss1 += sj;
        else if (jt == 2) ss2 += sj; else ss3 += sj;
      }
    }
    ss0 += __shfl_xor(ss0, 16, 64);  ss0 += __shfl_xor(ss0, 32, 64);
    ss1 += __shfl_xor(ss1, 16, 64);  ss1 += __shfl_xor(ss1, 32, 64);
    ss2 += __shfl_xor(ss2, 16, 64);  ss2 += __shfl_xor(ss2, 32, 64);
    ss3 += __shfl_xor(ss3, 16, 64);  ss3 += __shfl_xor(ss3, 32, 64);
    float sel = (q == 0) ? ss0 : (q == 1) ? ss1 : (q == 2) ? ss2 : ss3;
    sqws[(size_t)c * N_ + n0 + w * 64 + L] = sel;   // = 64 * sq
  };

  for (int ci2 = 0; ci2 < 4; ++ci2) {
    const int cA = c0 + ci2 * 2;
    __syncthreads();   // drains stage of plane(cA) into A0s
    STAGE(pl + (size_t)(ci2 * 2 + 1) * 12288, A1s);
    if (t < 32)
      __builtin_amdgcn_global_load_lds(
          (const unsigned int*)(Amut + (size_t)(cA + 1) * D_ + t * 4),
          (unsigned int*)&amus[1][0], 16, 0, 0);
    compute(A0s, &amus[0][0], cA);

    __syncthreads();   // drains stage of plane(cA+1) into A1s
    if (ci2 < 3) {
      STAGE(pl + (size_t)(ci2 * 2 + 2) * 12288, A0s);
      if (t < 32)
        __builtin_amdgcn_global_load_lds(
            (const unsigned int*)(Amut + (size_t)(cA + 2) * D_ + t * 4),
            (unsigned int*)&amus[0][0], 16, 0, 0);
    }
    compute(A1s, &amus[1][0], cA + 1);
  }
#undef STAGE
}

// ---------------------------------------------------------------------------
// softmax v2. sqws now holds 64*sq (A pre-scaled by 8) -> fold 1/64 into gamma
// exactly (pow2). Otherwise unchanged.
__global__ __launch_bounds__(256) void softmax_k(const float* __restrict__ sqws,
                                                 const float* __restrict__ gptr,
                                                 float* __restrict__ out) {
  __shared__ float s_ld[256][36];   // pad 36: f4-aligned rows, conflict-free reads
  __shared__ float red[8][32];
  __shared__ float red2[8][32];
  const int t = threadIdx.x;
  const int n0 = blockIdx.x * 32;
  const float gamma = *gptr * 0.015625f;   // gamma / 64
#pragma unroll
  for (int it = 0; it < 8; ++it) {
    int f = it * 256 + t;
    int c = f >> 3, nq = f & 7;
    *(float4*)&s_ld[c][nq * 4] = *(const float4*)&sqws[(size_t)c * N_ + n0 + nq * 4];
  }
  __syncthreads();
  const int nl = t & 31;
  const int cg = t >> 5;
  float mxp = -1e30f;
#pragma unroll
  for (int cc = 0; cc < 32; ++cc)
    mxp = fmaxf(mxp, gamma * s_ld[cg * 32 + cc][nl]);
  red[cg][nl] = mxp;
  __syncthreads();
  float mx = red[0][nl];
#pragma unroll
  for (int g2 = 1; g2 < 8; ++g2) mx = fmaxf(mx, red[g2][nl]);
  float ex[32];
  float z = 0.f;
#pragma unroll
  for (int cc = 0; cc < 32; ++cc) {
    ex[cc] = __expf(gamma * s_ld[cg * 32 + cc][nl] - mx);
    z += ex[cc];
  }
  red2[cg][nl] = z;
  __syncthreads();
  float zz = red2[0][nl];
#pragma unroll
  for (int g2 = 1; g2 < 8; ++g2) zz += red2[g2][nl];
  float rz = 1.f / zz;
#pragma unroll
  for (int cc = 0; cc < 32; ++cc)
    out[(size_t)(D_ + cg * 32 + cc) * N_ + n0 + nl] = ex[cc] * rz;
}

// ---------------------------------------------------------------------------
extern "C" void kernel_launch(void* const* d_in, const int* in_sizes, int n_in,
                              void* d_out, int out_size, void* d_ws, size_t ws_size,
                              hipStream_t stream) {
  const float* X   = (const float*)d_in[0];
  const float* NA  = (const float*)d_in[1];
  const float* Nmu = (const float*)d_in[2];
  const float* g   = (const float*)d_in[3];
  float* out = (float*)d_out;
  char* ws = (char*)d_ws;

  unsigned char* Xf6  = (unsigned char*)(ws);                  // 1 MB
  unsigned char* Af6s = (unsigned char*)(ws + 1048576);        // 3.0 MB (256 x 12288)
  float* Amut         = (float*)(ws + 5242880);                // 128 KB
  float* sqws         = (float*)(ws + 5373952);                // 8.39 MB

  hipLaunchKernelGGL(prep_k, dim3(512), dim3(256), 0, stream,
                     X, out, Xf6, NA, Af6s, Nmu, Amut);
  hipLaunchKernelGGL(main_k, dim3(1024), dim3(256), 0, stream,
                     Af6s, Xf6, Amut, sqws);
  hipLaunchKernelGGL(softmax_k, dim3(N_ / 32), dim3(256), 0, stream, sqws, g, out);
}

// Round 3
// 114.836 us; speedup vs baseline: 1.0113x; 1.0113x over previous
//
#include <hip/hip_runtime.h>

#define D_ 128
#define N_ 8192
#define K_ 256

typedef __attribute__((ext_vector_type(4))) float f4;    // 4 fp32
typedef __attribute__((ext_vector_type(8))) int i8v;     // 8 x i32 (MFMA operand)
typedef __attribute__((ext_vector_type(4))) int i4v;     // 4 x i32 (16 B)

// ---------------------------------------------------------------------------
// fp6 e2m3 helpers. Code: bit5 sign, bits4:3 exponent E (bias 1), bits2:0 M.
// Values: E=0 -> M/8 (subnormal, step .125, max .875); E>=1 -> (8+M)/8 * 2^(E-1).
// Max 7.5. Encoded value set = {0..15}/8  U  {16..30 step2}/8  U  {32..60 step4}/8.
__device__ __forceinline__ int enc6(float v) {
  unsigned s = (__float_as_uint(v) >> 31) << 5;
  float a = fminf(fabsf(v), 7.5f);
  int code;
  if (a < 2.f) {
    code = (int)rintf(a * 8.f);              // 0..16 ; 16 == (2<<3)|0 == 2.0 OK
  } else if (a < 4.f) {
    code = 16 + ((int)rintf(a * 4.f) - 8);   // 16..24 ; 24 == (3<<3)|0 == 4.0 OK
  } else {
    code = 24 + ((int)rintf(a * 2.f) - 8);   // 24..31 (7.5 -> 31)
  }
  return code | (int)s;
}

__device__ __forceinline__ float dec6(int c) {
  int M = c & 7, E = (c >> 3) & 3;
  int mant = (E == 0) ? M : (8 + M);
  float sc = (E <= 1) ? 0.125f : (E == 2 ? 0.25f : 0.5f);
  float v = (float)mant * sc;
  return (c & 32) ? -v : v;
}

// ---------------------------------------------------------------------------
// prep_k: fused prep_x + prep_a(+amu). Flat grid of 512 blocks.
//   blocks 0..255   : X (fp32 [D][N]) -> Xf6 (fp6, [n][4 q-chunks of 32B], 24 B
//                     data + 8 B pad per chunk) + exact fp32 copy of X into out.
//   blocks 256..511 : N_A -> Af6s (fp6 codes of 8*A, frag-ordered, 12288 B/plane:
//                     region0 [dtl][L][16B] then region1 [dtl][L][8B]) + fused
//                     negated amu computed from the DECODED fp6 values.
// A pre-scaled by 8 (8A ~ N(0,0.71) fits e2m3's 7.5 max); sq scaled by 64,
// folded into gamma (exact pow2) in softmax_k. UNCHANGED from round 2
// (verified correct, absmax 9.8e-4).
__global__ __launch_bounds__(256) void prep_k(
    const float* __restrict__ X, float* __restrict__ out,
    unsigned char* __restrict__ Xf6, const float* __restrict__ NA,
    unsigned char* __restrict__ Af6s, const float* __restrict__ Nmu,
    float* __restrict__ Amut) {
  __shared__ __align__(16) char smem[21568];
  const int t = threadIdx.x;
  const int id = blockIdx.x;

  if (id < 256) {
    // ---------------- prep_x role ----------------
    float (*tile)[65] = (float (*)[65])smem;   // 64 x 65 floats = 16.6 KB
    const int n0 = (id & 127) * 64;
    const int e0 = (id >> 7) * 64;
    const int col = t & 63;
    const int r4 = t >> 6;
    for (int rr = 0; rr < 64; rr += 4) {
      int e = rr + r4;
      float v = X[(size_t)(e0 + e) * N_ + n0 + col];
      tile[e][col] = v;
      out[(size_t)(e0 + e) * N_ + n0 + col] = v;   // exact fp32 copy of X
    }
    __syncthreads();
    // fp6 pack: 256 tasks = 64 n x 2 q-chunks x 2 halves (16 elements = 96 bits)
    const int nl = t >> 2;
    const int ql = (t >> 1) & 1;
    const int h = t & 1;
    unsigned long long lo = 0; unsigned int hi = 0;
#pragma unroll
    for (int j = 0; j < 16; ++j) {
      unsigned long long c = (unsigned long long)enc6(tile[ql * 32 + h * 16 + j][nl]);
      const int pos = 6 * j;
      if (pos <= 58) {
        lo |= c << pos;
      } else if (pos < 64) {
        lo |= c << pos;
        hi |= (unsigned int)(c >> (64 - pos));
      } else {
        hi |= (unsigned int)(c << (pos - 64));
      }
    }
    unsigned char* dst = Xf6 + (size_t)(n0 + nl) * 128 + (e0 / 32 + ql) * 32 + h * 12;
    *(unsigned int*)(dst + 0) = (unsigned int)lo;
    *(unsigned int*)(dst + 4) = (unsigned int)(lo >> 32);
    *(unsigned int*)(dst + 8) = hi;
  } else {
    // ---------------- prep_a (+amu) role ----------------
    const int aid = id - 256;
    const int dtl = aid & 7;           // d-tile of 16
    const int c0 = (aid >> 3) * 8;     // 8 c per block (32 groups)
    unsigned char* AT = (unsigned char*)smem;        // fp6 CODES [cl][d*136+e], 8*2184=17472 B
    float* mu_s = (float*)(smem + 17472);            // [cl][e], 8*128*4 = 4096 B
    {
      const int cl = t & 7;
      const int er = t >> 3;
#pragma unroll
      for (int pass = 0; pass < 4; ++pass) {
        int e = pass * 32 + er;
        mu_s[cl * 128 + e] = Nmu[(size_t)e * K_ + c0 + cl];
      }
    }
    // load + encode A*8 -> fp6 codes; float4 across 4 consecutive c
    const int c4 = t & 1;
    const int pe = t >> 1;
#pragma unroll 4
    for (int iter = 0; iter < 16; ++iter) {
      int p = iter * 128 + pe;
      int d = p >> 7, e = p & 127;
      float4 v = *(const float4*)&NA[((size_t)(dtl * 16 + d) * D_ + e) * K_ + c0 + c4 * 4];
      AT[(c4 * 4 + 0) * 2184 + d * 136 + e] = (unsigned char)enc6(v.x * 8.f);
      AT[(c4 * 4 + 1) * 2184 + d * 136 + e] = (unsigned char)enc6(v.y * 8.f);
      AT[(c4 * 4 + 2) * 2184 + d * 136 + e] = (unsigned char)enc6(v.z * 8.f);
      AT[(c4 * 4 + 3) * 2184 + d * 136 + e] = (unsigned char)enc6(v.w * 8.f);
    }
    __syncthreads();
    // fused amu from DECODED (x8-scaled) values; negated for the MFMA C-operand
    if (t < 128) {
      const int d_loc = t >> 3;
      const int cl = t & 7;
      const unsigned char* row = &AT[cl * 2184 + d_loc * 136];
      const float* mr = &mu_s[cl * 128];
      float s = 0.f;
#pragma unroll
      for (int j = 0; j < 16; ++j) {             // 16 x int2 (8 codes each)
        int2 v = *(const int2*)(row + j * 8);
        const int e0i = j * 8;
        s += dec6(v.x & 63) * mr[e0i + 0];
        s += dec6((v.x >> 8) & 63) * mr[e0i + 1];
        s += dec6((v.x >> 16) & 63) * mr[e0i + 2];
        s += dec6((v.x >> 24) & 63) * mr[e0i + 3];
        s += dec6(v.y & 63) * mr[e0i + 4];
        s += dec6((v.y >> 8) & 63) * mr[e0i + 5];
        s += dec6((v.y >> 16) & 63) * mr[e0i + 6];
        s += dec6((v.y >> 24) & 63) * mr[e0i + 7];
      }
      Amut[(size_t)(c0 + cl) * D_ + dtl * 16 + d_loc] = -s;
    }
    // write phase: 512 tasks (cl 0..7 x L 0..63): pack lane L's 32 codes
    // (row m=L&15, elements k=(L>>4)*32 + 0..31) into 24 B = 192 bits.
#pragma unroll
    for (int r = 0; r < 2; ++r) {
      const int task = r * 256 + t;
      const int cl = task >> 6;
      const int L = task & 63;
      const unsigned char* cp = AT + cl * 2184 + (L & 15) * 136 + (L >> 4) * 32;
      unsigned long long w0 = 0, w1 = 0, w2 = 0;
#pragma unroll
      for (int g = 0; g < 4; ++g) {             // 4 x int2 = 8 dwords of 4 codes
        int2 dv = *(const int2*)(cp + g * 8);
#pragma unroll
        for (int half = 0; half < 2; ++half) {
          unsigned int d = (half == 0) ? (unsigned int)dv.x : (unsigned int)dv.y;
          unsigned long long g24 =
              (unsigned long long)((d & 63u) | ((d >> 8) & 63u) << 6 |
                                   ((d >> 16) & 63u) << 12 | ((d >> 24) & 63u) << 18);
          const int pos = (g * 2 + half) * 24;
          if (pos < 64) {
            w0 |= g24 << pos;
            if (pos > 40) w1 |= g24 >> (64 - pos);
          } else if (pos < 128) {
            w1 |= g24 << (pos - 64);
            if (pos - 64 > 40) w2 |= g24 >> (128 - pos);
          } else {
            w2 |= g24 << (pos - 128);
          }
        }
      }
      unsigned char* plane = Af6s + (size_t)(c0 + cl) * 12288;
      ulonglong2 val; val.x = w0; val.y = w1;
      *(ulonglong2*)(plane + dtl * 1024 + L * 16) = val;                 // region0
      *(unsigned long long*)(plane + 8192 + dtl * 512 + L * 8) = w2;     // region1
    }
  }
}

// ---------------------------------------------------------------------------
// main (MX-fp6 e2m3, K=128, cbsz=blgp=2). NEW this round: pk-vectorized
// epilogue. Round-2 post-mortem: the scalar square-accumulate was 8 VALU per
// MFMA (~2050 cyc/SIMD/plane), equal to the fp6 MFMA pipe (~2830) -> kernel
// was VALU-bound and the fp6 rate never showed. Now: sv_jt = fma(acc,acc,sv_jt)
// elementwise on f4 (-> v_pk_fma_f32, 2 instr/MFMA), horizontal sum ONCE per
// plane. VALU drops to ~750 cyc/SIMD/plane -> cleanly MFMA-bound at fp6 rate.
__global__ __launch_bounds__(256, 4) void main_k(
    const unsigned char* __restrict__ Af6s, const unsigned char* __restrict__ Xf6,
    const float* __restrict__ Amut, float* __restrict__ sqws) {
  __shared__ unsigned char A0s[12288];
  __shared__ unsigned char A1s[12288];
  __shared__ float amus[2][D_];
  const int t = threadIdx.x;
  const int w = t >> 6;
  const int L = t & 63;
  const int m = L & 15;
  const int q = L >> 4;

  const int id = blockIdx.x;
  const int xcd = id & 7;
  const int s = id >> 3;
  const int yb = xcd * 4 + (s & 3);   // c-group 0..31 (4 per XCD)
  const int xb = s >> 2;              // n-tile 0..31
  const int n0 = xb * 256;
  const int c0 = yb * 8;

  // persistent X B-frags: lane holds n = n0+w*64+jt*16+m, k = q*32 + [0..31]
  i8v xf[4];
#pragma unroll
  for (int jt = 0; jt < 4; ++jt) {
    const unsigned char* xr = Xf6 + (size_t)(n0 + w * 64 + jt * 16 + m) * 128 + q * 32;
    i4v x0 = *(const i4v*)(xr);
    int2 x1 = *(const int2*)(xr + 16);
    i8v f;
    f[0] = x0[0]; f[1] = x0[1]; f[2] = x0[2]; f[3] = x0[3];
    f[4] = x1.x;  f[5] = x1.y;  f[6] = 0;     f[7] = 0;
    xf[jt] = f;
  }

  const unsigned char* pl = Af6s + (size_t)c0 * 12288;

#define STAGE(SRC, DST)                                                          \
  {                                                                              \
    _Pragma("unroll")                                                            \
    for (int it_ = 0; it_ < 3; ++it_)                                            \
      __builtin_amdgcn_global_load_lds(                                          \
          (const unsigned int*)((SRC) + (it_ * 256 + t) * 16),                   \
          (unsigned int*)((DST) + (it_ * 256 + w * 64) * 16), 16, 0, 0);         \
  }

  STAGE(pl, A0s);
  if (t < 32)
    __builtin_amdgcn_global_load_lds((const unsigned int*)(Amut + (size_t)c0 * D_ + t * 4),
                                     (unsigned int*)&amus[0][0], 16, 0, 0);

  auto compute = [&](const unsigned char* buf, const float* amurow, int c) {
    f4 sv0 = {0.f, 0.f, 0.f, 0.f};
    f4 sv1 = sv0, sv2 = sv0, sv3 = sv0;
    i8v a;
    a[6] = 0; a[7] = 0;                       // fp6 uses only regs 0..5; hoisted
#pragma unroll
    for (int dtl = 0; dtl < 8; ++dtl) {
      i4v p0 = *(const i4v*)(buf + dtl * 1024 + L * 16);            // bits 0..127
      int2 p1 = *(const int2*)(buf + 8192 + dtl * 512 + L * 8);     // bits 128..191
      a[0] = p0[0]; a[1] = p0[1]; a[2] = p0[2]; a[3] = p0[3];
      a[4] = p1.x;  a[5] = p1.y;
      f4 camu = *(const f4*)&amurow[dtl * 16 + q * 4];   // = -(8A)_q . mu slice
      f4 acc0 = __builtin_amdgcn_mfma_scale_f32_16x16x128_f8f6f4(
          a, xf[0], camu, 2, 2, 0, 0x7f7f7f7f, 0, 0x7f7f7f7f);
      f4 acc1 = __builtin_amdgcn_mfma_scale_f32_16x16x128_f8f6f4(
          a, xf[1], camu, 2, 2, 0, 0x7f7f7f7f, 0, 0x7f7f7f7f);
      f4 acc2 = __builtin_amdgcn_mfma_scale_f32_16x16x128_f8f6f4(
          a, xf[2], camu, 2, 2, 0, 0x7f7f7f7f, 0, 0x7f7f7f7f);
      f4 acc3 = __builtin_amdgcn_mfma_scale_f32_16x16x128_f8f6f4(
          a, xf[3], camu, 2, 2, 0, 0x7f7f7f7f, 0, 0x7f7f7f7f);
      sv0 = __builtin_elementwise_fma(acc0, acc0, sv0);   // v_pk_fma_f32 x2
      sv1 = __builtin_elementwise_fma(acc1, acc1, sv1);
      sv2 = __builtin_elementwise_fma(acc2, acc2, sv2);
      sv3 = __builtin_elementwise_fma(acc3, acc3, sv3);
    }
    // horizontal sums once per plane
    float ss0 = (sv0[0] + sv0[1]) + (sv0[2] + sv0[3]);
    float ss1 = (sv1[0] + sv1[1]) + (sv1[2] + sv1[3]);
    float ss2 = (sv2[0] + sv2[1]) + (sv2[2] + sv2[3]);
    float ss3 = (sv3[0] + sv3[1]) + (sv3[2] + sv3[3]);
    ss0 += __shfl_xor(ss0, 16, 64);  ss0 += __shfl_xor(ss0, 32, 64);
    ss1 += __shfl_xor(ss1, 16, 64);  ss1 += __shfl_xor(ss1, 32, 64);
    ss2 += __shfl_xor(ss2, 16, 64);  ss2 += __shfl_xor(ss2, 32, 64);
    ss3 += __shfl_xor(ss3, 16, 64);  ss3 += __shfl_xor(ss3, 32, 64);
    float sel = (q == 0) ? ss0 : (q == 1) ? ss1 : (q == 2) ? ss2 : ss3;
    sqws[(size_t)c * N_ + n0 + w * 64 + L] = sel;   // = 64 * sq
  };

  for (int ci2 = 0; ci2 < 4; ++ci2) {
    const int cA = c0 + ci2 * 2;
    __syncthreads();   // drains stage of plane(cA) into A0s
    STAGE(pl + (size_t)(ci2 * 2 + 1) * 12288, A1s);
    if (t < 32)
      __builtin_amdgcn_global_load_lds(
          (const unsigned int*)(Amut + (size_t)(cA + 1) * D_ + t * 4),
          (unsigned int*)&amus[1][0], 16, 0, 0);
    compute(A0s, &amus[0][0], cA);

    __syncthreads();   // drains stage of plane(cA+1) into A1s
    if (ci2 < 3) {
      STAGE(pl + (size_t)(ci2 * 2 + 2) * 12288, A0s);
      if (t < 32)
        __builtin_amdgcn_global_load_lds(
            (const unsigned int*)(Amut + (size_t)(cA + 2) * D_ + t * 4),
            (unsigned int*)&amus[0][0], 16, 0, 0);
    }
    compute(A1s, &amus[1][0], cA + 1);
  }
#undef STAGE
}

// ---------------------------------------------------------------------------
// softmax v2. sqws holds 64*sq -> fold 1/64 into gamma exactly (pow2).
// UNCHANGED from round 2.
__global__ __launch_bounds__(256) void softmax_k(const float* __restrict__ sqws,
                                                 const float* __restrict__ gptr,
                                                 float* __restrict__ out) {
  __shared__ float s_ld[256][36];   // pad 36: f4-aligned rows, conflict-free reads
  __shared__ float red[8][32];
  __shared__ float red2[8][32];
  const int t = threadIdx.x;
  const int n0 = blockIdx.x * 32;
  const float gamma = *gptr * 0.015625f;   // gamma / 64
#pragma unroll
  for (int it = 0; it < 8; ++it) {
    int f = it * 256 + t;
    int c = f >> 3, nq = f & 7;
    *(float4*)&s_ld[c][nq * 4] = *(const float4*)&sqws[(size_t)c * N_ + n0 + nq * 4];
  }
  __syncthreads();
  const int nl = t & 31;
  const int cg = t >> 5;
  float mxp = -1e30f;
#pragma unroll
  for (int cc = 0; cc < 32; ++cc)
    mxp = fmaxf(mxp, gamma * s_ld[cg * 32 + cc][nl]);
  red[cg][nl] = mxp;
  __syncthreads();
  float mx = red[0][nl];
#pragma unroll
  for (int g2 = 1; g2 < 8; ++g2) mx = fmaxf(mx, red[g2][nl]);
  float ex[32];
  float z = 0.f;
#pragma unroll
  for (int cc = 0; cc < 32; ++cc) {
    ex[cc] = __expf(gamma * s_ld[cg * 32 + cc][nl] - mx);
    z += ex[cc];
  }
  red2[cg][nl] = z;
  __syncthreads();
  float zz = red2[0][nl];
#pragma unroll
  for (int g2 = 1; g2 < 8; ++g2) zz += red2[g2][nl];
  float rz = 1.f / zz;
#pragma unroll
  for (int cc = 0; cc < 32; ++cc)
    out[(size_t)(D_ + cg * 32 + cc) * N_ + n0 + nl] = ex[cc] * rz;
}

// ---------------------------------------------------------------------------
extern "C" void kernel_launch(void* const* d_in, const int* in_sizes, int n_in,
                              void* d_out, int out_size, void* d_ws, size_t ws_size,
                              hipStream_t stream) {
  const float* X   = (const float*)d_in[0];
  const float* NA  = (const float*)d_in[1];
  const float* Nmu = (const float*)d_in[2];
  const float* g   = (const float*)d_in[3];
  float* out = (float*)d_out;
  char* ws = (char*)d_ws;

  unsigned char* Xf6  = (unsigned char*)(ws);                  // 1 MB
  unsigned char* Af6s = (unsigned char*)(ws + 1048576);        // 3.0 MB (256 x 12288)
  float* Amut         = (float*)(ws + 5242880);                // 128 KB
  float* sqws         = (float*)(ws + 5373952);                // 8.39 MB

  hipLaunchKernelGGL(prep_k, dim3(512), dim3(256), 0, stream,
                     X, out, Xf6, NA, Af6s, Nmu, Amut);
  hipLaunchKernelGGL(main_k, dim3(1024), dim3(256), 0, stream,
                     Af6s, Xf6, Amut, sqws);
  hipLaunchKernelGGL(softmax_k, dim3(N_ / 32), dim3(256), 0, stream, sqws, g, out);
}

// Round 4
// 113.774 us; speedup vs baseline: 1.0208x; 1.0093x over previous
//
#include <hip/hip_runtime.h>

#define D_ 128
#define N_ 8192
#define K_ 256

typedef __attribute__((ext_vector_type(4))) float f4;    // 4 fp32
typedef __attribute__((ext_vector_type(8))) int i8v;     // 8 x i32 (32 B fp8 frag)
typedef __attribute__((ext_vector_type(4))) int i4v;     // 4 x i32 (16 B)

// ---------------------------------------------------------------------------
// prep_k: fused prep_x + prep_a(+amu). Flat grid of 512 blocks:
//   blocks 0..255   : X (fp32 [D][N]) -> Xf8 (fp8 [N][D]) transpose + exact
//                     fp32 copy of X into out rows 0..D-1.
//   blocks 256..511 : N_A (fp32 [D][D][K]) -> Af8s (fp8, frag-ordered) +
//                     fused negated amu (computed from quantized A via HW
//                     fp8 decode, so the MFMA C-operand is exactly consistent).
// RESTORED to the round-0 fp8 version (verified best: 112.5/113.8 us,
// absmax 6.1e-4). The fp6 arc (rounds 2-3) showed no MFMA-rate win on this
// instruction mix and cost precision headroom; reverted.
__global__ __launch_bounds__(256) void prep_k(
    const float* __restrict__ X, float* __restrict__ out,
    unsigned char* __restrict__ Xf8, const float* __restrict__ NA,
    unsigned char* __restrict__ Af8s, const float* __restrict__ Nmu,
    float* __restrict__ Amut) {
  __shared__ __align__(16) char smem[21568];
  const int t = threadIdx.x;
  const int id = blockIdx.x;

  if (id < 256) {
    // ---------------- prep_x role ----------------
    float (*tile)[65] = (float (*)[65])smem;   // 64 x 65 floats = 16.6 KB
    const int n0 = (id & 127) * 64;
    const int e0 = (id >> 7) * 64;
    const int col = t & 63;
    const int r4 = t >> 6;
    for (int rr = 0; rr < 64; rr += 4) {
      int e = rr + r4;
      float v = X[(size_t)(e0 + e) * N_ + n0 + col];
      tile[e][col] = v;
      out[(size_t)(e0 + e) * N_ + n0 + col] = v;   // exact fp32 copy of X
    }
    __syncthreads();
    const int chunk = t & 15;
    for (int iter = 0; iter < 4; ++iter) {
      int nl = iter * 16 + (t >> 4);
      float v0 = tile[chunk * 4 + 0][nl];
      float v1 = tile[chunk * 4 + 1][nl];
      float v2 = tile[chunk * 4 + 2][nl];
      float v3 = tile[chunk * 4 + 3][nl];
      int pk = __builtin_amdgcn_cvt_pk_fp8_f32(v0, v1, 0, false);
      pk = __builtin_amdgcn_cvt_pk_fp8_f32(v2, v3, pk, true);
      *(int*)&Xf8[(size_t)(n0 + nl) * D_ + e0 + chunk * 4] = pk;
    }
  } else {
    // ---------------- prep_a (+amu) role ----------------
    const int aid = id - 256;
    const int dtl = aid & 7;           // d-tile of 16
    const int c0 = (aid >> 3) * 8;     // 8 c per block (32 groups)
    unsigned char* AT = (unsigned char*)smem;        // [cl][d*136+e], 8*2184=17472 B
    float* mu_s = (float*)(smem + 17472);            // [cl][e], 8*128*4 = 4096 B
    // load mu: cl = t&7, er = t>>3; 4 passes of 32 e
    {
      const int cl = t & 7;
      const int er = t >> 3;
#pragma unroll
      for (int pass = 0; pass < 4; ++pass) {
        int e = pass * 32 + er;
        mu_s[cl * 128 + e] = Nmu[(size_t)e * K_ + c0 + cl];
      }
    }
    // load + convert A: float4 across 4 consecutive c; c4 = t&1, pe = t>>1
    const int c4 = t & 1;
    const int pe = t >> 1;
#pragma unroll 4
    for (int iter = 0; iter < 16; ++iter) {
      int p = iter * 128 + pe;
      int d = p >> 7, e = p & 127;
      float4 v = *(const float4*)&NA[((size_t)(dtl * 16 + d) * D_ + e) * K_ + c0 + c4 * 4];
      int pk0 = __builtin_amdgcn_cvt_pk_fp8_f32(v.x, v.x, 0, false);
      int pk1 = __builtin_amdgcn_cvt_pk_fp8_f32(v.y, v.y, 0, false);
      int pk2 = __builtin_amdgcn_cvt_pk_fp8_f32(v.z, v.z, 0, false);
      int pk3 = __builtin_amdgcn_cvt_pk_fp8_f32(v.w, v.w, 0, false);
      AT[(c4 * 4 + 0) * 2184 + d * 136 + e] = (unsigned char)(pk0 & 0xff);
      AT[(c4 * 4 + 1) * 2184 + d * 136 + e] = (unsigned char)(pk1 & 0xff);
      AT[(c4 * 4 + 2) * 2184 + d * 136 + e] = (unsigned char)(pk2 & 0xff);
      AT[(c4 * 4 + 3) * 2184 + d * 136 + e] = (unsigned char)(pk3 & 0xff);
    }
    __syncthreads();
    // fused amu: 128 entries (16 d x 8 c); negated for the MFMA C-operand
    if (t < 128) {
      const int d_loc = t >> 3;
      const int cl = t & 7;
      const unsigned char* row = &AT[cl * 2184 + d_loc * 136];
      const float* mr = &mu_s[cl * 128];
      float s = 0.f;
#pragma unroll
      for (int j = 0; j < 16; ++j) {             // 16 x int2 (8 e each)
        int2 v = *(const int2*)(row + j * 8);
        const int e0 = j * 8;
        s += __builtin_amdgcn_cvt_f32_fp8(v.x, 0) * mr[e0 + 0];
        s += __builtin_amdgcn_cvt_f32_fp8(v.x, 1) * mr[e0 + 1];
        s += __builtin_amdgcn_cvt_f32_fp8(v.x, 2) * mr[e0 + 2];
        s += __builtin_amdgcn_cvt_f32_fp8(v.x, 3) * mr[e0 + 3];
        s += __builtin_amdgcn_cvt_f32_fp8(v.y, 0) * mr[e0 + 4];
        s += __builtin_amdgcn_cvt_f32_fp8(v.y, 1) * mr[e0 + 5];
        s += __builtin_amdgcn_cvt_f32_fp8(v.y, 2) * mr[e0 + 6];
        s += __builtin_amdgcn_cvt_f32_fp8(v.y, 3) * mr[e0 + 7];
      }
      Amut[(size_t)(c0 + cl) * D_ + dtl * 16 + d_loc] = -s;
    }
    // write phase: 16 units (ucl 0..7, h 0..1), each one wave x 16 B per lane
    const int w = t >> 6, L = t & 63, q = L >> 4, m = L & 15;
#pragma unroll
    for (int it = 0; it < 4; ++it) {
      int u = w + it * 4;                 // 0..15
      int ucl = u >> 1, h = u & 1;
      const unsigned char* base = AT + ucl * 2184 + m * 136 + q * 32 + h * 16;
      unsigned long long lo = *(const unsigned long long*)(base);
      unsigned long long hi = *(const unsigned long long*)(base + 8);
      ulonglong2 val; val.x = lo; val.y = hi;
      *(ulonglong2*)(Af8s + (size_t)(c0 + ucl) * 16384 + dtl * 2048 + h * 1024 + L * 16) = val;
    }
  }
}

// ---------------------------------------------------------------------------
// main (MX-fp8, K=128 per instruction): sq[c][n] = sum_d (sum_e A X - Amu)^2
// grid (N/256, K/8), block 256 (4 waves) -- the verified round-0 structure.
// ONE change vs round 0: pk-vectorized epilogue (sv = fma(acc,acc,sv) on f4,
// horizontal sum once per plane) replacing the 8-scalar-VALU-per-MFMA chain.
// fp8 MFMA pipe (4420 cyc/plane/SIMD) still dominates VALU (~900), so this is
// neutral-to-slightly-positive; it tightens the interleave inside the known
// 80%-of-floor gap. fp6 arc reverted (no rate win materialized, rounds 2-3).
__global__ __launch_bounds__(256, 4) void main_k(
    const unsigned char* __restrict__ Af8s, const unsigned char* __restrict__ Xf8,
    const float* __restrict__ Amut, float* __restrict__ sqws) {
  __shared__ unsigned char A0s[16384];
  __shared__ unsigned char A1s[16384];
  __shared__ float amus[2][D_];
  const int t = threadIdx.x;
  const int w = t >> 6;
  const int L = t & 63;
  const int m = L & 15;
  const int q = L >> 4;
  const int n0 = blockIdx.x * 256;
  const int c0 = blockIdx.y * 8;

  // persistent X B-frags: lane holds n = n0+w*64+jt*16+m, k = q*32 + [0..31] (32 B)
  i8v xf[4];
#pragma unroll
  for (int jt = 0; jt < 4; ++jt)
    xf[jt] = *(const i8v*)(Xf8 + (size_t)(n0 + w * 64 + jt * 16 + m) * D_ + q * 32);

  const unsigned char* pl = Af8s + (size_t)c0 * 16384;

#define STAGE(SRC, DST)                                                          \
  {                                                                              \
    _Pragma("unroll")                                                            \
    for (int it_ = 0; it_ < 4; ++it_)                                            \
      __builtin_amdgcn_global_load_lds(                                          \
          (const unsigned int*)((SRC) + (it_ * 256 + t) * 16),                   \
          (unsigned int*)((DST) + (it_ * 256 + w * 64) * 16), 16, 0, 0);         \
  }

  STAGE(pl, A0s);
  if (t < 32)
    __builtin_amdgcn_global_load_lds((const unsigned int*)(Amut + (size_t)c0 * D_ + t * 4),
                                     (unsigned int*)&amus[0][0], 16, 0, 0);

  auto compute = [&](const unsigned char* buf, const float* amurow, int c) {
    f4 sv0 = {0.f, 0.f, 0.f, 0.f};
    f4 sv1 = sv0, sv2 = sv0, sv3 = sv0;
#pragma unroll
    for (int dtl = 0; dtl < 8; ++dtl) {
      i4v lo = *(const i4v*)(buf + dtl * 2048 + L * 16);          // k = q*32+0..15
      i4v hi = *(const i4v*)(buf + dtl * 2048 + 1024 + L * 16);   // k = q*32+16..31
      i8v a;
      a[0] = lo[0]; a[1] = lo[1]; a[2] = lo[2]; a[3] = lo[3];
      a[4] = hi[0]; a[5] = hi[1]; a[6] = hi[2]; a[7] = hi[3];
      f4 camu = *(const f4*)&amurow[dtl * 16 + q * 4];   // = -Amu slice
      f4 acc0 = __builtin_amdgcn_mfma_scale_f32_16x16x128_f8f6f4(
          a, xf[0], camu, 0, 0, 0, 0x7f7f7f7f, 0, 0x7f7f7f7f);
      f4 acc1 = __builtin_amdgcn_mfma_scale_f32_16x16x128_f8f6f4(
          a, xf[1], camu, 0, 0, 0, 0x7f7f7f7f, 0, 0x7f7f7f7f);
      f4 acc2 = __builtin_amdgcn_mfma_scale_f32_16x16x128_f8f6f4(
          a, xf[2], camu, 0, 0, 0, 0x7f7f7f7f, 0, 0x7f7f7f7f);
      f4 acc3 = __builtin_amdgcn_mfma_scale_f32_16x16x128_f8f6f4(
          a, xf[3], camu, 0, 0, 0, 0x7f7f7f7f, 0, 0x7f7f7f7f);
      sv0 = __builtin_elementwise_fma(acc0, acc0, sv0);   // v_pk_fma_f32 x2
      sv1 = __builtin_elementwise_fma(acc1, acc1, sv1);
      sv2 = __builtin_elementwise_fma(acc2, acc2, sv2);
      sv3 = __builtin_elementwise_fma(acc3, acc3, sv3);
    }
    // horizontal sums once per plane
    float ss0 = (sv0[0] + sv0[1]) + (sv0[2] + sv0[3]);
    float ss1 = (sv1[0] + sv1[1]) + (sv1[2] + sv1[3]);
    float ss2 = (sv2[0] + sv2[1]) + (sv2[2] + sv2[3]);
    float ss3 = (sv3[0] + sv3[1]) + (sv3[2] + sv3[3]);
    ss0 += __shfl_xor(ss0, 16, 64);  ss0 += __shfl_xor(ss0, 32, 64);
    ss1 += __shfl_xor(ss1, 16, 64);  ss1 += __shfl_xor(ss1, 32, 64);
    ss2 += __shfl_xor(ss2, 16, 64);  ss2 += __shfl_xor(ss2, 32, 64);
    ss3 += __shfl_xor(ss3, 16, 64);  ss3 += __shfl_xor(ss3, 32, 64);
    float sel = (q == 0) ? ss0 : (q == 1) ? ss1 : (q == 2) ? ss2 : ss3;
    sqws[(size_t)c * N_ + n0 + w * 64 + L] = sel;
  };

  for (int ci2 = 0; ci2 < 4; ++ci2) {
    const int cA = c0 + ci2 * 2;
    __syncthreads();   // drains stage of plane(cA) into A0s
    STAGE(pl + (size_t)(ci2 * 2 + 1) * 16384, A1s);
    if (t < 32)
      __builtin_amdgcn_global_load_lds(
          (const unsigned int*)(Amut + (size_t)(cA + 1) * D_ + t * 4),
          (unsigned int*)&amus[1][0], 16, 0, 0);
    compute(A0s, &amus[0][0], cA);

    __syncthreads();   // drains stage of plane(cA+1) into A1s
    if (ci2 < 3) {
      STAGE(pl + (size_t)(ci2 * 2 + 2) * 16384, A0s);
      if (t < 32)
        __builtin_amdgcn_global_load_lds(
            (const unsigned int*)(Amut + (size_t)(cA + 2) * D_ + t * 4),
            (unsigned int*)&amus[0][0], 16, 0, 0);
    }
    compute(A1s, &amus[1][0], cA + 1);
  }
#undef STAGE
}

// ---------------------------------------------------------------------------
// softmax v2: 32-n tiles (256 blocks), float4 loads, exp values in registers.
// RESTORED to round-0 (plain gamma; sqws holds unscaled sq again).
__global__ __launch_bounds__(256) void softmax_k(const float* __restrict__ sqws,
                                                 const float* __restrict__ gptr,
                                                 float* __restrict__ out) {
  __shared__ float s_ld[256][36];   // pad 36: f4-aligned rows, conflict-free reads
  __shared__ float red[8][32];
  __shared__ float red2[8][32];
  const int t = threadIdx.x;
  const int n0 = blockIdx.x * 32;
  const float gamma = *gptr;
#pragma unroll
  for (int it = 0; it < 8; ++it) {
    int f = it * 256 + t;
    int c = f >> 3, nq = f & 7;
    *(float4*)&s_ld[c][nq * 4] = *(const float4*)&sqws[(size_t)c * N_ + n0 + nq * 4];
  }
  __syncthreads();
  const int nl = t & 31;
  const int cg = t >> 5;
  float mxp = -1e30f;
#pragma unroll
  for (int cc = 0; cc < 32; ++cc)
    mxp = fmaxf(mxp, gamma * s_ld[cg * 32 + cc][nl]);
  red[cg][nl] = mxp;
  __syncthreads();
  float mx = red[0][nl];
#pragma unroll
  for (int g2 = 1; g2 < 8; ++g2) mx = fmaxf(mx, red[g2][nl]);
  float ex[32];
  float z = 0.f;
#pragma unroll
  for (int cc = 0; cc < 32; ++cc) {
    ex[cc] = __expf(gamma * s_ld[cg * 32 + cc][nl] - mx);
    z += ex[cc];
  }
  red2[cg][nl] = z;
  __syncthreads();
  float zz = red2[0][nl];
#pragma unroll
  for (int g2 = 1; g2 < 8; ++g2) zz += red2[g2][nl];
  float rz = 1.f / zz;
#pragma unroll
  for (int cc = 0; cc < 32; ++cc)
    out[(size_t)(D_ + cg * 32 + cc) * N_ + n0 + nl] = ex[cc] * rz;
}

// ---------------------------------------------------------------------------
extern "C" void kernel_launch(void* const* d_in, const int* in_sizes, int n_in,
                              void* d_out, int out_size, void* d_ws, size_t ws_size,
                              hipStream_t stream) {
  const float* X   = (const float*)d_in[0];
  const float* NA  = (const float*)d_in[1];
  const float* Nmu = (const float*)d_in[2];
  const float* g   = (const float*)d_in[3];
  float* out = (float*)d_out;
  char* ws = (char*)d_ws;

  unsigned char* Xf8  = (unsigned char*)(ws);                  // 1 MB
  unsigned char* Af8s = (unsigned char*)(ws + 1048576);        // 4.19 MB
  float* Amut         = (float*)(ws + 5242880);                // 128 KB
  float* sqws         = (float*)(ws + 5373952);                // 8.39 MB

  hipLaunchKernelGGL(prep_k, dim3(512), dim3(256), 0, stream,
                     X, out, Xf8, NA, Af8s, Nmu, Amut);
  hipLaunchKernelGGL(main_k, dim3(N_ / 256, K_ / 8), dim3(256), 0, stream,
                     Af8s, Xf8, Amut, sqws);
  hipLaunchKernelGGL(softmax_k, dim3(N_ / 32), dim3(256), 0, stream, sqws, g, out);
}